// Round 9
// baseline (714.291 us; speedup 1.0000x reference)
//
#include <hip/hip_runtime.h>
#include <math.h>

#define TPB 512
#define TPB_R 512
#define BUCKET_SHIFT 11
#define BUCKET_SIZE 2048            // nodes per reduction bucket (11 bits local)
#define MAX_NB 512                  // slack fast path supports up to 512 buckets
#define SUB 8192                    // edges per block in bin_slack
#define CAPSHIFT 17
#define CAP (1u << CAPSHIFT)        // 131072 slots/bucket = 2x mean at E=32M,NB=489
#define SRC_BITS 20
#define SRC_MASK ((1u << SRC_BITS) - 1u)
#define LOC_MASK ((unsigned)(BUCKET_SIZE - 1))

// native clang vector types: required by __builtin_nontemporal_load
typedef int   int4n   __attribute__((ext_vector_type(4)));
typedef unsigned int uint4n __attribute__((ext_vector_type(4)));

// ---------- scan helper ----------

__device__ inline unsigned wave_scan_incl(unsigned v) {
#pragma unroll
    for (int d = 1; d < 64; d <<= 1) {
        unsigned n = __shfl_up(v, d, 64);
        if ((int)(threadIdx.x & 63) >= d) v += n;
    }
    return v;
}

// ---------- K1: tile-local counting sort -> slack-allocated packed buckets ----------
// (verified round 5). Order within a bucket is irrelevant; each bucket owns
// CAP slots (2x multinomial mean, sigma~256 -> ~250 sigma headroom); each
// block reserves its chunk with one global atomicAdd per (block,bucket),
// hidden under the rank phase. LDS-staged sort retained: round-1
// direct-scatter measured 6x HBM write amplification without it.

__global__ __launch_bounds__(TPB)
void bin_slack(const int* __restrict__ src, const int* __restrict__ dst,
               unsigned* __restrict__ gcur, unsigned* __restrict__ packed,
               long long E, int NB) {
    __shared__ unsigned A[MAX_NB];            // per-bucket count -> excl start
    __shared__ unsigned B[MAX_NB];            // running rank cursor
    __shared__ unsigned gbase[MAX_NB];        // reserved global chunk base
    __shared__ unsigned wtot[8];
    __shared__ unsigned short sKey[SUB];      // sorted bucket ids
    __shared__ unsigned sPack[SUB];           // sorted payloads
    int g = blockIdx.x, t = threadIdx.x;

    long long subBase = (long long)g * SUB;
    long long subEnd = subBase + SUB; if (subEnd > E) subEnd = E;
    int subCount = (int)(subEnd - subBase);

    A[t] = 0u;                                 // NB <= MAX_NB == TPB
    __syncthreads();

    // load 16 edges/thread into regs, build keys/packs, LDS histogram
    unsigned key[16], pk[16];
#pragma unroll
    for (int r = 0; r < 4; ++r) {
        long long ebase = subBase + ((long long)(r * TPB + t)) * 4;
        int4n sv = (int4n)0, dv = (int4n)0;
        if (ebase + 4 <= subEnd) {
            sv = __builtin_nontemporal_load((const int4n*)(src + ebase));
            dv = __builtin_nontemporal_load((const int4n*)(dst + ebase));
        } else if (ebase < subEnd) {
            int n = (int)(subEnd - ebase);
            const int* sp = src + ebase;
            const int* dp = dst + ebase;
            sv.x = sp[0]; dv.x = dp[0];
            if (n > 1) { sv.y = sp[1]; dv.y = dp[1]; }
            if (n > 2) { sv.z = sp[2]; dv.z = dp[2]; }
        }
        long long navail = subEnd - ebase;
        int n = (navail < 0) ? 0 : ((navail > 4) ? 4 : (int)navail);
        unsigned dd[4] = {(unsigned)dv.x, (unsigned)dv.y, (unsigned)dv.z, (unsigned)dv.w};
        unsigned ss[4] = {(unsigned)sv.x, (unsigned)sv.y, (unsigned)sv.z, (unsigned)sv.w};
#pragma unroll
        for (int c = 0; c < 4; ++c) {
            int j = r * 4 + c;
            if (c < n) {
                unsigned k = dd[c] >> BUCKET_SHIFT;
                key[j] = k;
                pk[j] = ((dd[c] & LOC_MASK) << SRC_BITS) | ss[c];
                atomicAdd(&A[k], 1u);
            } else {
                key[j] = 0xFFFFFFFFu;
                pk[j] = 0u;
            }
        }
    }
    __syncthreads();

    // exclusive scan of the 512 per-bucket counts (1 value/thread)
    unsigned a = A[t];
    unsigned incl = wave_scan_incl(a);
    int lane = t & 63, wid = t >> 6;
    if (lane == 63) wtot[wid] = incl;
    __syncthreads();
    if (t == 0) {
        unsigned c = 0;
#pragma unroll
        for (int i = 0; i < 8; ++i) { unsigned tv = wtot[i]; wtot[i] = c; c += tv; }
    }
    __syncthreads();
    unsigned excl = wtot[wid] + incl - a;
    A[t] = excl;
    B[t] = excl;
    __syncthreads();

    // reserve this block's chunk in bucket t's slack region (latency hides
    // under the rank/scatter phase below; consumed after the next barrier)
    if (t < NB && a > 0u) gbase[t] = atomicAdd(&gcur[t], a);

    // rank + scatter into sorted LDS staging
#pragma unroll
    for (int j = 0; j < 16; ++j) {
        if (key[j] != 0xFFFFFFFFu) {
            unsigned r = atomicAdd(&B[key[j]], 1u);
            sKey[r] = (unsigned short)key[j];
            sPack[r] = pk[j];
        }
    }
    __syncthreads();

    // stream sorted staging to global: consecutive jj in a bucket run land
    // in consecutive slots of that bucket's slack region -> coalesced runs
    unsigned limit = ((unsigned)NB) << CAPSHIFT;
    for (int jj = t; jj < subCount; jj += TPB) {
        unsigned b = sKey[jj];
        unsigned gpos = ((unsigned)b << CAPSHIFT) + gbase[b] + (unsigned)jj - A[b];
        if (gpos < limit) packed[gpos] = sPack[jj];   // guard vs pathological skew
    }
}

// ---------- K2: reduce with Q32.32 u64 LDS accumulation (both layers) ----------
// Measured LDS-atomic ladder for this kernel (within-probe A/B, r5-r8):
// ds_add_f32 = 186us, ds_add_u32 = 176us, ds_add_u64 = ~153us. Deploying the
// measured winner (u64) for both layers. Exactness: layer 1 term < 2^32,
// sum < 70*2^32 ~ 2^38; layer 2 term < 70*2^32, sum < 2^45 -- both << 2^64.
// double conversion is exact; strictly MORE accurate than f32 ordering.
// The ~150us floor itself is a per-CU divergent-access serialization
// (rounds 2/6 nulls: occupancy- and MLP-insensitive).

__global__ __launch_bounds__(TPB_R)
void reduce_bucket_u64(const unsigned* __restrict__ packed,
                       const unsigned* __restrict__ fill,
                       const float* __restrict__ in, float* __restrict__ out,
                       int N, int final_layer) {
    __shared__ unsigned long long acc[BUCKET_SIZE];   // 16 KB
    int b = blockIdx.x, t = threadIdx.x;
    for (int k = t; k < BUCKET_SIZE; k += TPB_R) acc[k] = 0ull;
    __syncthreads();
    unsigned cnt = fill[b]; if (cnt > CAP) cnt = CAP;   // guard vs skew
    const unsigned* base = packed + ((size_t)b << CAPSHIFT);
    unsigned n4 = cnt >> 2;
    const uint4n* p4 = (const uint4n*)base;
    const float S = 4294967296.0f;   // 2^32 (exact exponent shift on f32)
    unsigned i = (unsigned)t;
    for (; i + 3u * TPB_R < n4; i += 4u * TPB_R) {
        uint4n q0 = __builtin_nontemporal_load(p4 + i);
        uint4n q1 = __builtin_nontemporal_load(p4 + i + TPB_R);
        uint4n q2 = __builtin_nontemporal_load(p4 + i + 2u * TPB_R);
        uint4n q3 = __builtin_nontemporal_load(p4 + i + 3u * TPB_R);
        unsigned long long f0  = (unsigned long long)(fmaxf(in[q0.x & SRC_MASK], 0.f) * S);
        unsigned long long f1  = (unsigned long long)(fmaxf(in[q0.y & SRC_MASK], 0.f) * S);
        unsigned long long f2  = (unsigned long long)(fmaxf(in[q0.z & SRC_MASK], 0.f) * S);
        unsigned long long f3  = (unsigned long long)(fmaxf(in[q0.w & SRC_MASK], 0.f) * S);
        unsigned long long f4  = (unsigned long long)(fmaxf(in[q1.x & SRC_MASK], 0.f) * S);
        unsigned long long f5  = (unsigned long long)(fmaxf(in[q1.y & SRC_MASK], 0.f) * S);
        unsigned long long f6  = (unsigned long long)(fmaxf(in[q1.z & SRC_MASK], 0.f) * S);
        unsigned long long f7  = (unsigned long long)(fmaxf(in[q1.w & SRC_MASK], 0.f) * S);
        unsigned long long f8  = (unsigned long long)(fmaxf(in[q2.x & SRC_MASK], 0.f) * S);
        unsigned long long f9  = (unsigned long long)(fmaxf(in[q2.y & SRC_MASK], 0.f) * S);
        unsigned long long f10 = (unsigned long long)(fmaxf(in[q2.z & SRC_MASK], 0.f) * S);
        unsigned long long f11 = (unsigned long long)(fmaxf(in[q2.w & SRC_MASK], 0.f) * S);
        unsigned long long f12 = (unsigned long long)(fmaxf(in[q3.x & SRC_MASK], 0.f) * S);
        unsigned long long f13 = (unsigned long long)(fmaxf(in[q3.y & SRC_MASK], 0.f) * S);
        unsigned long long f14 = (unsigned long long)(fmaxf(in[q3.z & SRC_MASK], 0.f) * S);
        unsigned long long f15 = (unsigned long long)(fmaxf(in[q3.w & SRC_MASK], 0.f) * S);
        atomicAdd(&acc[q0.x >> SRC_BITS], f0);
        atomicAdd(&acc[q0.y >> SRC_BITS], f1);
        atomicAdd(&acc[q0.z >> SRC_BITS], f2);
        atomicAdd(&acc[q0.w >> SRC_BITS], f3);
        atomicAdd(&acc[q1.x >> SRC_BITS], f4);
        atomicAdd(&acc[q1.y >> SRC_BITS], f5);
        atomicAdd(&acc[q1.z >> SRC_BITS], f6);
        atomicAdd(&acc[q1.w >> SRC_BITS], f7);
        atomicAdd(&acc[q2.x >> SRC_BITS], f8);
        atomicAdd(&acc[q2.y >> SRC_BITS], f9);
        atomicAdd(&acc[q2.z >> SRC_BITS], f10);
        atomicAdd(&acc[q2.w >> SRC_BITS], f11);
        atomicAdd(&acc[q3.x >> SRC_BITS], f12);
        atomicAdd(&acc[q3.y >> SRC_BITS], f13);
        atomicAdd(&acc[q3.z >> SRC_BITS], f14);
        atomicAdd(&acc[q3.w >> SRC_BITS], f15);
    }
    for (; i < n4; i += TPB_R) {
        uint4n q = __builtin_nontemporal_load(p4 + i);
        unsigned long long f0 = (unsigned long long)(fmaxf(in[q.x & SRC_MASK], 0.f) * S);
        unsigned long long f1 = (unsigned long long)(fmaxf(in[q.y & SRC_MASK], 0.f) * S);
        unsigned long long f2 = (unsigned long long)(fmaxf(in[q.z & SRC_MASK], 0.f) * S);
        unsigned long long f3 = (unsigned long long)(fmaxf(in[q.w & SRC_MASK], 0.f) * S);
        atomicAdd(&acc[q.x >> SRC_BITS], f0);
        atomicAdd(&acc[q.y >> SRC_BITS], f1);
        atomicAdd(&acc[q.z >> SRC_BITS], f2);
        atomicAdd(&acc[q.w >> SRC_BITS], f3);
    }
    for (unsigned j = n4 * 4u + (unsigned)t; j < cnt; j += TPB_R) {
        unsigned p = base[j];
        atomicAdd(&acc[p >> SRC_BITS],
                  (unsigned long long)(fmaxf(in[p & SRC_MASK], 0.f) * S));
    }
    __syncthreads();
    const double INV = 1.0 / 4294967296.0;   // acc < 2^45: double is exact
    for (int k = t; k < BUCKET_SIZE; k += TPB_R) {
        int node = b * BUCKET_SIZE + k;
        if (node < N) {
            float v = (float)((double)acc[k] * INV);
            out[node] = final_layer ? 1.f / (1.f + expf(-v)) : v;
        }
    }
}

// ---------- fallback (atomic path) ----------

__global__ void scatter_add_relu(const int* __restrict__ src,
                                 const int* __restrict__ dst,
                                 const float* __restrict__ in,
                                 float* __restrict__ out,
                                 long long E, long long E4) {
    long long i = (long long)blockIdx.x * blockDim.x + threadIdx.x;
    long long stride = (long long)gridDim.x * blockDim.x;
    const int4* src4 = (const int4*)src;
    const int4* dst4 = (const int4*)dst;
    for (long long v = i; v < E4; v += stride) {
        int4 s = src4[v];
        int4 d = dst4[v];
        atomicAdd(&out[d.x], fmaxf(in[s.x], 0.0f));
        atomicAdd(&out[d.y], fmaxf(in[s.y], 0.0f));
        atomicAdd(&out[d.z], fmaxf(in[s.z], 0.0f));
        atomicAdd(&out[d.w], fmaxf(in[s.w], 0.0f));
    }
    for (long long e = E4 * 4 + i; e < E; e += stride)
        atomicAdd(&out[dst[e]], fmaxf(in[src[e]], 0.0f));
}

__global__ void sigmoid_inplace(float* __restrict__ out, int n) {
    int i = blockIdx.x * blockDim.x + threadIdx.x;
    if (i < n) {
        float v = out[i];
        out[i] = 1.0f / (1.0f + expf(-v));
    }
}

// ---------- launch ----------

extern "C" void kernel_launch(void* const* d_in, const int* in_sizes, int n_in,
                              void* d_out, int out_size, void* d_ws, size_t ws_size,
                              hipStream_t stream) {
    const float* x = (const float*)d_in[0];
    const int* ei = (const int*)d_in[1];
    const int N = in_sizes[0];
    const long long E = (long long)in_sizes[1] / 2;
    const int* src = ei;        // row 0
    const int* dst = ei + E;    // row 1
    float* out = (float*)d_out;

    const int NB = (N + BUCKET_SIZE - 1) / BUCKET_SIZE;
    const int GB = (int)((E + SUB - 1) / SUB);   // bin blocks

    // workspace layout: cursors + h1 + slack-allocated packed
    size_t off = 0;
    auto alloc = [&](size_t bytes) {
        size_t o = off;
        off = (off + bytes + 15) & ~(size_t)15;
        return o;
    };
    char* ws = (char*)d_ws;
    size_t gcurOff   = alloc((size_t)MAX_NB * 4);
    size_t h1Off     = alloc((size_t)N * 4);
    size_t packedOff = alloc(((size_t)NB << CAPSHIFT) * 4);

    const bool fast = (N <= (1 << SRC_BITS)) && (NB <= MAX_NB) &&
                      (off <= ws_size) &&
                      ((E / (NB > 0 ? NB : 1)) <= (long long)(CAP / 2));

    if (fast) {
        unsigned* gcur   = (unsigned*)(ws + gcurOff);
        float*    h1     = (float*)(ws + h1Off);
        unsigned* packed = (unsigned*)(ws + packedOff);

        (void)hipMemsetAsync(gcur, 0, (size_t)MAX_NB * 4, stream);
        bin_slack<<<GB, TPB, 0, stream>>>(src, dst, gcur, packed, E, NB);
        // layer 1: Q32.32 u64 accumulation (measured best: ~153us, round 7)
        reduce_bucket_u64<<<NB, TPB_R, 0, stream>>>(packed, gcur, x, h1, N, 0);
        // layer 2: same kernel + fused sigmoid
        reduce_bucket_u64<<<NB, TPB_R, 0, stream>>>(packed, gcur, h1, out, N, 1);
    } else {
        float* h1 = (float*)ws;
        (void)hipMemsetAsync(h1, 0, (size_t)N * sizeof(float), stream);
        (void)hipMemsetAsync(out, 0, (size_t)N * sizeof(float), stream);
        const long long E4 = ((E & 3) == 0) ? (E >> 2) : 0;
        const long long work = (E4 > 0) ? E4 : E;
        long long blocks_ll = (work + 255) / 256;
        if (blocks_ll > 131072) blocks_ll = 131072;
        const int blocks = (int)blocks_ll;
        scatter_add_relu<<<blocks, 256, 0, stream>>>(src, dst, x, h1, E, E4);
        scatter_add_relu<<<blocks, 256, 0, stream>>>(src, dst, h1, out, E, E4);
        sigmoid_inplace<<<(N + 255) / 256, 256, 0, stream>>>(out, N);
    }
}